// Round 7
// baseline (217.595 us; speedup 1.0000x reference)
//
#include <hip/hip_runtime.h>

// Window attention, bf16-MFMA (R7): wave = head, barrier-free attention core.
// 256 threads = 4 waves per block, 1 block = 1 window. Wave h does head h
// end-to-end: QKV -> in-register repack (4-lane shfl, generalizes R4's proven
// P-exchange) -> fused QK^T+exp+PV per q-tile -> ao. LDS only for x (16KB) and
// ao (16KB) = 32KB, 2 barriers. launch_bounds(256,4): min-BLOCKS semantics
// (R3-R6 evidence) -> VGPR cap 128, 4 blocks/CU = 16 waves/CU.

typedef __attribute__((ext_vector_type(8))) short bf16x8;
typedef __attribute__((ext_vector_type(4))) float f32x4;
typedef __attribute__((ext_vector_type(4))) __bf16 bf16x4;

#define MFMA16(a, b, c) __builtin_amdgcn_mfma_f32_16x16x32_bf16(a, b, c, 0, 0, 0)

__device__ __forceinline__ uint2 pack4bf(float a, float b, float c, float d) {
    bf16x4 v; v[0] = (__bf16)a; v[1] = (__bf16)b; v[2] = (__bf16)c; v[3] = (__bf16)d;
    union { bf16x4 v; uint2 u; } pun; pun.v = v; return pun.u;
}

__device__ __forceinline__ uint2 shfl_u2(uint2 v, int src) {
    uint2 r;
    r.x = (unsigned)__shfl((int)v.x, src, 64);
    r.y = (unsigned)__shfl((int)v.y, src, 64);
    return r;
}

// Generic D->frag repack (proven as R4/R6's P-exchange). Input: two packed
// D-tiles p0,p1: lane (cn,g') holds X[row = 16*t + 4*g' + r][col = cn], r=0..3.
// Output frag: lane (cn,g) holds X[row = 8g..8g+7][col = cn] as bf16x8.
__device__ __forceinline__ bf16x8 repack32(uint2 p0, uint2 p1,
                                           int esrc, int osrc, bool hi) {
    uint2 a0 = shfl_u2(p0, esrc);
    uint2 a1 = shfl_u2(p1, esrc);
    uint2 b0 = shfl_u2(p0, osrc);
    uint2 b1 = shfl_u2(p1, osrc);
    union { uint4 u; bf16x8 v; } pun;
    pun.u.x = hi ? a1.x : a0.x;
    pun.u.y = hi ? a1.y : a0.y;
    pun.u.z = hi ? b1.x : b0.x;
    pun.u.w = hi ? b1.y : b0.y;
    return pun.v;
}

// Swizzled [64][128] bf16 tile offset (row 256B); <=2-way banks for all uses.
__device__ __forceinline__ int ao_off(int tok, int c) {
    return (tok << 7) + (((((c >> 3) & 15) ^ (tok & 7)) << 3)) + (c & 7);
}

// ---- prep: weights fp32->bf16; bias repacked bf16 [h][nq][g][ti*4+r] * log2(e) ----
__global__ void prep_kernel(const float* __restrict__ qkv_w,
                            const float* __restrict__ proj_w,
                            const float* __restrict__ bias_table,
                            ushort* __restrict__ wq_bf,
                            ushort* __restrict__ wp_bf,
                            ushort* __restrict__ biasb) {
    int i = blockIdx.x * 256 + threadIdx.x;
    if (i < 49152) {
        union { __bf16 b; ushort s; } u; u.b = (__bf16)qkv_w[i];
        wq_bf[i] = u.s;
    }
    if (i < 16384) {
        union { __bf16 b; ushort s; } u; u.b = (__bf16)proj_w[i];
        wp_bf[i] = u.s;
        int h = i >> 12, nq = (i >> 6) & 63, g = (i >> 4) & 3, ti = (i >> 2) & 3, r = i & 3;
        int nk = 16 * ti + 4 * g + r;
        int idx = ((nq >> 3) - (nk >> 3) + 7) * 15 + ((nq & 7) - (nk & 7) + 7);
        union { __bf16 b; ushort s; } ub;
        ub.b = (__bf16)(bias_table[idx * 4 + h] * 1.4426950408889634f);
        biasb[i] = ub.s;
    }
}

__global__ __launch_bounds__(256, 4)
void winattn_mfma(const float* __restrict__ x,
                  const float* __restrict__ qkv_b,
                  const float* __restrict__ proj_b,
                  const ushort* __restrict__ wq_bf,
                  const ushort* __restrict__ wp_bf,
                  const ushort* __restrict__ biasb,
                  float* __restrict__ out) {
    __shared__ ushort S[16384];        // 32KB: xs [0,8192) | ao [8192,16384)

    const int tid = threadIdx.x;
    const size_t w = blockIdx.x;
    const int h  = __builtin_amdgcn_readfirstlane(tid >> 6);  // 0..3: wave = head
    const int l  = tid & 63;
    const int g  = (l >> 4) & 3;   // 0..3
    const int cn = l & 15;         // 0..15

    ushort* xs  = S;               // x bf16 [64][128] swizzled
    ushort* aoL = S + 8192;        // ao bf16 [64][128] swizzled

    const int esrc = ((l & 16) << 1) + cn;   // lane (cn, 2*(g&1))
    const int osrc = esrc + 16;              // lane (cn, 2*(g&1)+1)
    const bool hi  = (l & 32) != 0;          // g >= 2
    const f32x4 zero = (f32x4){0.f, 0.f, 0.f, 0.f};

    // ---- stage A: x -> bf16 LDS tile ----
    const float* xg = x + w * 8192;
    #pragma unroll
    for (int it = 0; it < 8; ++it) {
        int f4 = tid + 256 * it;          // 0..2047
        int n = f4 >> 5, c4 = f4 & 31;
        float4 xv = ((const float4*)xg)[f4];
        *(uint2*)&xs[ao_off(n, 4 * c4)] = pack4bf(xv.x, xv.y, xv.z, xv.w);
    }
    __syncthreads();                                   // (1) xs ready

    // ---- QKV pass 1: q,k (swapped: D[d][tok]) ----
    bf16x8 qa[4], ka[4];
    {
        f32x4 aq[2][4], ak[2][4];
        #pragma unroll
        for (int i = 0; i < 2; ++i)
            #pragma unroll
            for (int tn = 0; tn < 4; ++tn) { aq[i][tn] = zero; ak[i][tn] = zero; }
        #pragma unroll
        for (int kc = 0; kc < 4; ++kc) {
            bf16x8 xf[4];
            #pragma unroll
            for (int tn = 0; tn < 4; ++tn)
                xf[tn] = *(const bf16x8*)&xs[ao_off(16 * tn + cn, 8 * g + 32 * kc)];
            #pragma unroll
            for (int i = 0; i < 2; ++i) {
                const int wrow = 32 * h + 16 * i + cn;
                const bf16x8 wq = *(const bf16x8*)&wq_bf[(size_t)(wrow      ) * 128 + 8 * g + 32 * kc];
                const bf16x8 wk = *(const bf16x8*)&wq_bf[(size_t)(wrow + 128) * 128 + 8 * g + 32 * kc];
                #pragma unroll
                for (int tn = 0; tn < 4; ++tn) {
                    aq[i][tn] = MFMA16(wq, xf[tn], aq[i][tn]);
                    ak[i][tn] = MFMA16(wk, xf[tn], ak[i][tn]);
                }
            }
        }
        // bias + pack + repack: qa[tj]/ka[tn] = frag[tok=16t+cn][d=8g..8g+7]
        #pragma unroll
        for (int t = 0; t < 4; ++t) {
            uint2 pq[2], pk2[2];
            #pragma unroll
            for (int i = 0; i < 2; ++i) {
                const float4 bq = *(const float4*)&qkv_b[      32 * h + 16 * i + 4 * g];
                const float4 bk = *(const float4*)&qkv_b[128 + 32 * h + 16 * i + 4 * g];
                f32x4 q4 = aq[i][t], k4 = ak[i][t];
                pq[i]  = pack4bf(q4[0] + bq.x, q4[1] + bq.y, q4[2] + bq.z, q4[3] + bq.w);
                pk2[i] = pack4bf(k4[0] + bk.x, k4[1] + bk.y, k4[2] + bk.z, k4[3] + bk.w);
            }
            qa[t] = repack32(pq[0],  pq[1],  esrc, osrc, hi);
            ka[t] = repack32(pk2[0], pk2[1], esrc, osrc, hi);
        }
    }

    // ---- QKV pass 2: v (unswapped: D[tok][d]) ----
    bf16x8 va[2][2];   // [d-tile ta][tok-slice kk]
    {
        f32x4 av[4][2];
        #pragma unroll
        for (int tn = 0; tn < 4; ++tn)
            #pragma unroll
            for (int i = 0; i < 2; ++i) av[tn][i] = zero;
        #pragma unroll
        for (int kc = 0; kc < 4; ++kc) {
            bf16x8 xf[4];
            #pragma unroll
            for (int tn = 0; tn < 4; ++tn)
                xf[tn] = *(const bf16x8*)&xs[ao_off(16 * tn + cn, 8 * g + 32 * kc)];
            #pragma unroll
            for (int i = 0; i < 2; ++i) {
                const bf16x8 wv = *(const bf16x8*)&wq_bf[(size_t)(256 + 32 * h + 16 * i + cn) * 128 + 8 * g + 32 * kc];
                #pragma unroll
                for (int tn = 0; tn < 4; ++tn)
                    av[tn][i] = MFMA16(xf[tn], wv, av[tn][i]);
            }
        }
        const float bv0 = qkv_b[256 + 32 * h + cn];
        const float bv1 = qkv_b[256 + 32 * h + 16 + cn];
        uint2 pv[4][2];
        #pragma unroll
        for (int tn = 0; tn < 4; ++tn) {
            f32x4 v0 = av[tn][0], v1 = av[tn][1];
            pv[tn][0] = pack4bf(v0[0] + bv0, v0[1] + bv0, v0[2] + bv0, v0[3] + bv0);
            pv[tn][1] = pack4bf(v1[0] + bv1, v1[1] + bv1, v1[2] + bv1, v1[3] + bv1);
        }
        #pragma unroll
        for (int ta = 0; ta < 2; ++ta)
            #pragma unroll
            for (int kk = 0; kk < 2; ++kk)
                va[ta][kk] = repack32(pv[2 * kk][ta], pv[2 * kk + 1][ta], esrc, osrc, hi);
    }

    // ---- fused QK^T + exp + PV per q-tile tj (no S materialization) ----
    const float SCALE2 = 0.17677669529663687f * 1.4426950408889634f;  // scale*log2(e)
    #pragma unroll
    for (int tj = 0; tj < 4; ++tj) {
        const ushort* bp = biasb + (((h * 64 + 16 * tj + cn) * 4 + g) << 4);
        const uint4 bb0 = *(const uint4*)bp;
        const uint4 bb1 = *(const uint4*)(bp + 8);
        f32x4 sv[4];
        #pragma unroll
        for (int ti = 0; ti < 4; ++ti)
            sv[ti] = MFMA16(ka[ti], qa[tj], zero);       // D[nk][nq]
        float sum = 0.f;
        uint2 pkt[4];
        #pragma unroll
        for (int ti = 0; ti < 4; ++ti) {
            const uint4 q4 = (ti < 2) ? bb0 : bb1;
            const unsigned w0 = (ti & 1) ? q4.z : q4.x;
            const unsigned w1 = (ti & 1) ? q4.w : q4.y;
            const float b0 = __uint_as_float(w0 << 16);
            const float b1 = __uint_as_float(w0 & 0xffff0000u);
            const float b2 = __uint_as_float(w1 << 16);
            const float b3 = __uint_as_float(w1 & 0xffff0000u);
            f32x4 s4 = sv[ti];
            s4[0] = exp2f(fmaf(s4[0], SCALE2, b0));
            s4[1] = exp2f(fmaf(s4[1], SCALE2, b1));
            s4[2] = exp2f(fmaf(s4[2], SCALE2, b2));
            s4[3] = exp2f(fmaf(s4[3], SCALE2, b3));
            pkt[ti] = pack4bf(s4[0], s4[1], s4[2], s4[3]);
            sum += (s4[0] + s4[1]) + (s4[2] + s4[3]);
        }
        sum += __shfl_xor(sum, 16, 64);
        sum += __shfl_xor(sum, 32, 64);
        const float rs = 1.0f / sum;
        const bf16x8 pb0 = repack32(pkt[0], pkt[1], esrc, osrc, hi);  // P[nq][nk 0..31]
        const bf16x8 pb1 = repack32(pkt[2], pkt[3], esrc, osrc, hi);  // P[nq][nk 32..63]
        #pragma unroll
        for (int ta = 0; ta < 2; ++ta) {
            f32x4 o = MFMA16(va[ta][0], pb0, zero);
            o = MFMA16(va[ta][1], pb1, o);               // D[d][nq]
            *(uint2*)&aoL[ao_off(16 * tj + cn, 32 * h + 16 * ta + 4 * g)] =
                pack4bf(o[0] * rs, o[1] * rs, o[2] * rs, o[3] * rs);
        }
    }
    __syncthreads();                                   // (2) ao ready

    // ---- out projection (swapped): D[co][tok], wave h -> co tiles {2h, 2h+1} ----
    float* og = out + w * 8192;
    #pragma unroll
    for (int i = 0; i < 2; ++i) {
        const int prow = 16 * (2 * h + i) + cn;
        f32x4 po[4];
        #pragma unroll
        for (int tj = 0; tj < 4; ++tj) po[tj] = zero;
        #pragma unroll
        for (int kc = 0; kc < 4; ++kc) {
            const bf16x8 pf = *(const bf16x8*)&wp_bf[(size_t)prow * 128 + 8 * g + 32 * kc];
            #pragma unroll
            for (int tj = 0; tj < 4; ++tj) {
                const bf16x8 aof = *(const bf16x8*)&aoL[ao_off(16 * tj + cn, 8 * g + 32 * kc)];
                po[tj] = MFMA16(pf, aof, po[tj]);
            }
        }
        const int co0 = 16 * (2 * h + i) + 4 * g;
        const float4 pb4 = *(const float4*)&proj_b[co0];
        #pragma unroll
        for (int tj = 0; tj < 4; ++tj) {
            f32x4 pv = po[tj];
            float4 ov;
            ov.x = pv[0] + pb4.x; ov.y = pv[1] + pb4.y;
            ov.z = pv[2] + pb4.z; ov.w = pv[3] + pb4.w;
            *(float4*)&og[(16 * tj + cn) * 128 + co0] = ov;
        }
    }
}

extern "C" void kernel_launch(void* const* d_in, const int* in_sizes, int n_in,
                              void* d_out, int out_size, void* d_ws, size_t ws_size,
                              hipStream_t stream) {
    const float* x          = (const float*)d_in[0];
    const float* qkv_w      = (const float*)d_in[1];
    const float* qkv_b      = (const float*)d_in[2];
    const float* proj_w     = (const float*)d_in[3];
    const float* proj_b     = (const float*)d_in[4];
    const float* bias_table = (const float*)d_in[5];
    float* out = (float*)d_out;

    // ws layout: [0,98304) qkv_w bf16 | [98304,131072) proj_w bf16 | [131072,163840) biasb bf16
    ushort* wq_bf = (ushort*)d_ws;
    ushort* wp_bf = (ushort*)((char*)d_ws + 98304);
    ushort* biasb = (ushort*)((char*)d_ws + 131072);

    prep_kernel<<<dim3(192), dim3(256), 0, stream>>>(qkv_w, proj_w, bias_table, wq_bf, wp_bf, biasb);
    winattn_mfma<<<dim3(4096), dim3(256), 0, stream>>>(x, qkv_b, proj_b, wq_bf, wp_bf, biasb, out);
}

// Round 8
// 123.158 us; speedup vs baseline: 1.7668x; 1.7668x over previous
//
#include <hip/hip_runtime.h>

// Window attention, bf16-MFMA (R8): R6 body + 2 windows/block with T14
// prefetch (issue x loads for both windows at block start; window 1's x held
// in 16 VGPRs through window 0, written to its own LDS buffer late).
// 512 threads = 8 waves, waves (h,0),(h,1) share head h (R4/R6 proven layout).
// LDS 80KB: xb0[16K] | xb1[16K] | q[4][64][32] | k[4][64][32] | vT[4][32][64];
// ao[64][128] overlays vT after frag loads. 4 barriers/window.
// launch_bounds(512,2): min-BLOCKS semantics (R5/R6 evidence) -> VGPR cap 128.

typedef __attribute__((ext_vector_type(8))) short bf16x8;
typedef __attribute__((ext_vector_type(4))) float f32x4;
typedef __attribute__((ext_vector_type(4))) __bf16 bf16x4;

#define MFMA16(a, b, c) __builtin_amdgcn_mfma_f32_16x16x32_bf16(a, b, c, 0, 0, 0)

__device__ __forceinline__ uint2 pack4bf(float a, float b, float c, float d) {
    bf16x4 v; v[0] = (__bf16)a; v[1] = (__bf16)b; v[2] = (__bf16)c; v[3] = (__bf16)d;
    union { bf16x4 v; uint2 u; } pun; pun.v = v; return pun.u;
}

__device__ __forceinline__ uint2 shfl_u2(uint2 v, int src) {
    uint2 r;
    r.x = (unsigned)__shfl((int)v.x, src, 64);
    r.y = (unsigned)__shfl((int)v.y, src, 64);
    return r;
}

// Bijective in-row XOR swizzles (ushort units), 16B-slot granularity.
__device__ __forceinline__ int qk_off(int tok, int d) {   // [64][32] bf16, row 64B
    return (tok << 5) + (((((d >> 3) & 3) ^ ((tok >> 1) & 3)) << 3)) + (d & 7);
}
__device__ __forceinline__ int vt_off(int d, int tok) {   // [32][64] bf16, row 128B
    return (d << 6) + (((((tok >> 3) & 7) ^ (d & 7)) << 3)) + (tok & 7);
}
__device__ __forceinline__ int ao_off(int tok, int c) {   // [64][128] bf16, row 256B
    return (tok << 7) + (((((c >> 3) & 15) ^ (tok & 7)) << 3)) + (c & 7);
}

// ---- prep: weights fp32->bf16; bias repacked bf16 [h][nq][g][ti*4+r] * log2(e) ----
__global__ void prep_kernel(const float* __restrict__ qkv_w,
                            const float* __restrict__ proj_w,
                            const float* __restrict__ bias_table,
                            ushort* __restrict__ wq_bf,
                            ushort* __restrict__ wp_bf,
                            ushort* __restrict__ biasb) {
    int i = blockIdx.x * 256 + threadIdx.x;
    if (i < 49152) {
        union { __bf16 b; ushort s; } u; u.b = (__bf16)qkv_w[i];
        wq_bf[i] = u.s;
    }
    if (i < 16384) {
        union { __bf16 b; ushort s; } u; u.b = (__bf16)proj_w[i];
        wp_bf[i] = u.s;
        int h = i >> 12, nq = (i >> 6) & 63, g = (i >> 4) & 3, ti = (i >> 2) & 3, r = i & 3;
        int nk = 16 * ti + 4 * g + r;
        int idx = ((nq >> 3) - (nk >> 3) + 7) * 15 + ((nq & 7) - (nk & 7) + 7);
        union { __bf16 b; ushort s; } ub;
        ub.b = (__bf16)(bias_table[idx * 4 + h] * 1.4426950408889634f);
        biasb[i] = ub.s;
    }
}

__global__ __launch_bounds__(512, 2)
void winattn_mfma(const float* __restrict__ x,
                  const float* __restrict__ qkv_b,
                  const float* __restrict__ proj_b,
                  const ushort* __restrict__ wq_bf,
                  const ushort* __restrict__ wp_bf,
                  const ushort* __restrict__ biasb,
                  float* __restrict__ out) {
    __shared__ ushort S[40960];   // 80KB arena (see header)

    const int tid = threadIdx.x;
    const size_t wbase = (size_t)blockIdx.x * 2;
    const int h    = __builtin_amdgcn_readfirstlane(tid >> 7);        // 0..3 head
    const int half = __builtin_amdgcn_readfirstlane((tid >> 6) & 1);  // 0..1 wave-in-pair
    const int l  = tid & 63;
    const int g  = (l >> 4) & 3;  // 0..3
    const int cn = l & 15;        // 0..15

    ushort* xb0 = S;                       // [64][128] bf16 (swizzled), window 0
    ushort* xb1 = S + 8192;                // same, window 1
    ushort* qL  = S + 16384 + 2048 * h;    // [64][32]
    ushort* kL  = S + 24576 + 2048 * h;    // [64][32]
    ushort* vT  = S + 32768 + 2048 * h;    // [32][64]
    ushort* aoL = S + 32768;               // [64][128] overlays vT after frag loads

    const int an = tid >> 5;       // 0..15 (x-load row group)
    const int ac4 = tid & 31;      // 0..31 (x-load col float4)

    // ---- prologue: issue BOTH windows' x loads; write w0; hold w1 in regs ----
    const float* xg0 = x + wbase * 8192;
    float4 x0[4], xn[4];
    #pragma unroll
    for (int it = 0; it < 4; ++it)
        x0[it] = ((const float4*)xg0)[tid + 512 * it];
    #pragma unroll
    for (int it = 0; it < 4; ++it)
        xn[it] = ((const float4*)(xg0 + 8192))[tid + 512 * it];
    #pragma unroll
    for (int it = 0; it < 4; ++it) {
        float4 xv = x0[it];
        *(uint2*)&xb0[ao_off(an + 16 * it, 4 * ac4)] = pack4bf(xv.x, xv.y, xv.z, xv.w);
    }
    __syncthreads();                                   // B1: xb0 ready

    const float SCALE2 = 0.17677669529663687f * 1.4426950408889634f;  // scale*log2(e)
    const int esrc = ((l & 16) << 1) + cn;   // lane 32*(g&1)+cn
    const int osrc = esrc + 16;
    const bool hi = (l & 32) != 0;           // g>=2

    #pragma unroll
    for (int rep = 0; rep < 2; ++rep) {
        ushort* xs = rep ? xb1 : xb0;

        // ---- QKV projection MFMAs, d-half = half (acc in regs) ----
        f32x4 aq[4], ak[4], av[4];
        #pragma unroll
        for (int tn = 0; tn < 4; ++tn) {
            aq[tn] = (f32x4){0.f, 0.f, 0.f, 0.f};
            ak[tn] = (f32x4){0.f, 0.f, 0.f, 0.f};
            av[tn] = (f32x4){0.f, 0.f, 0.f, 0.f};
        }
        {
            const int wrow = 32 * h + 16 * half + cn;
            #pragma unroll 2
            for (int kc = 0; kc < 4; ++kc) {
                const bf16x8 wq = *(const bf16x8*)&wq_bf[(size_t)(wrow      ) * 128 + 8 * g + 32 * kc];
                const bf16x8 wk = *(const bf16x8*)&wq_bf[(size_t)(wrow + 128) * 128 + 8 * g + 32 * kc];
                const bf16x8 wv = *(const bf16x8*)&wq_bf[(size_t)(wrow + 256) * 128 + 8 * g + 32 * kc];
                #pragma unroll
                for (int tn = 0; tn < 4; ++tn) {
                    const bf16x8 xf = *(const bf16x8*)&xs[ao_off(16 * tn + cn, 8 * g + 32 * kc)];
                    aq[tn] = MFMA16(wq, xf, aq[tn]);   // D[d][tok]
                    ak[tn] = MFMA16(wk, xf, ak[tn]);   // D[d][tok]
                    av[tn] = MFMA16(xf, wv, av[tn]);   // D[tok][d]
                }
            }
        }
        if (rep) __syncthreads();        // gate: prior proj's ao reads drained

        // ---- write q/k/v (biased) into swizzled tiles ----
        {
            const float4 bq = *(const float4*)&qkv_b[      32 * h + 16 * half + 4 * g];
            const float4 bk = *(const float4*)&qkv_b[128 + 32 * h + 16 * half + 4 * g];
            const float  bv = qkv_b[256 + 32 * h + 16 * half + cn];
            #pragma unroll
            for (int tn = 0; tn < 4; ++tn) {
                f32x4 q4 = aq[tn], k4 = ak[tn], v4 = av[tn];
                *(uint2*)&qL[qk_off(16 * tn + cn, 16 * half + 4 * g)] =
                    pack4bf(q4[0] + bq.x, q4[1] + bq.y, q4[2] + bq.z, q4[3] + bq.w);
                *(uint2*)&kL[qk_off(16 * tn + cn, 16 * half + 4 * g)] =
                    pack4bf(k4[0] + bk.x, k4[1] + bk.y, k4[2] + bk.z, k4[3] + bk.w);
                *(uint2*)&vT[vt_off(16 * half + cn, 16 * tn + 4 * g)] =
                    pack4bf(v4[0] + bv, v4[1] + bv, v4[2] + bv, v4[3] + bv);
            }
        }
        __syncthreads();                 // B2: q/k/v ready

        // ---- frag loads (must complete before ao overlays vT) ----
        bf16x8 ka[4], qa[2], va[2][2];
        #pragma unroll
        for (int t = 0; t < 4; ++t)
            ka[t] = *(const bf16x8*)&kL[qk_off(16 * t + cn, 8 * g)];
        #pragma unroll
        for (int j2 = 0; j2 < 2; ++j2)
            qa[j2] = *(const bf16x8*)&qL[qk_off(16 * (2 * half + j2) + cn, 8 * g)];
        #pragma unroll
        for (int ta = 0; ta < 2; ++ta)
            #pragma unroll
            for (int kk = 0; kk < 2; ++kk)
                va[ta][kk] = *(const bf16x8*)&vT[vt_off(16 * ta + cn, 8 * g + 32 * kk)];
        __syncthreads();                 // B3: frag reads drained

        // ---- QK^T (swapped, own tj pair) ----
        f32x4 s[4][2];
        #pragma unroll
        for (int ti = 0; ti < 4; ++ti)
            #pragma unroll
            for (int j2 = 0; j2 < 2; ++j2)
                s[ti][j2] = (f32x4){0.f, 0.f, 0.f, 0.f};
        #pragma unroll
        for (int ti = 0; ti < 4; ++ti)
            #pragma unroll
            for (int j2 = 0; j2 < 2; ++j2)
                s[ti][j2] = MFMA16(ka[ti], qa[j2], s[ti][j2]);   // D[nk][nq]

        // ---- bias load ----
        uint4 bb[2][2];
        #pragma unroll
        for (int j2 = 0; j2 < 2; ++j2) {
            const int nq = 16 * (2 * half + j2) + cn;
            const ushort* bp = biasb + (((h * 64 + nq) * 4 + g) << 4);
            bb[j2][0] = *(const uint4*)bp;
            bb[j2][1] = *(const uint4*)(bp + 8);
        }

        // ---- softmax (no max-subtract) + in-register P exchange; P UNNORMALIZED ----
        bf16x8 pbf[2][2];
        float rs[2];
        #pragma unroll
        for (int j2 = 0; j2 < 2; ++j2) {
            float sum = 0.f;
            uint2 pk[4];
            #pragma unroll
            for (int ti = 0; ti < 4; ++ti) {
                const uint4 q4 = bb[j2][ti >> 1];
                const unsigned w0 = (ti & 1) ? q4.z : q4.x;
                const unsigned w1 = (ti & 1) ? q4.w : q4.y;
                const float b0 = __uint_as_float(w0 << 16);
                const float b1 = __uint_as_float(w0 & 0xffff0000u);
                const float b2 = __uint_as_float(w1 << 16);
                const float b3 = __uint_as_float(w1 & 0xffff0000u);
                f32x4 sv = s[ti][j2];
                sv[0] = exp2f(fmaf(sv[0], SCALE2, b0));
                sv[1] = exp2f(fmaf(sv[1], SCALE2, b1));
                sv[2] = exp2f(fmaf(sv[2], SCALE2, b2));
                sv[3] = exp2f(fmaf(sv[3], SCALE2, b3));
                pk[ti] = pack4bf(sv[0], sv[1], sv[2], sv[3]);
                sum += (sv[0] + sv[1]) + (sv[2] + sv[3]);
            }
            sum += __shfl_xor(sum, 16, 64);
            sum += __shfl_xor(sum, 32, 64);
            rs[j2] = 1.0f / sum;          // applied in PV epilogue (lane-local)
            #pragma unroll
            for (int kk = 0; kk < 2; ++kk) {
                uint2 a0 = shfl_u2(pk[2 * kk    ], esrc);
                uint2 a1 = shfl_u2(pk[2 * kk + 1], esrc);
                uint2 b0 = shfl_u2(pk[2 * kk    ], osrc);
                uint2 b1 = shfl_u2(pk[2 * kk + 1], osrc);
                uint2 A; A.x = hi ? a1.x : a0.x; A.y = hi ? a1.y : a0.y;
                uint2 B; B.x = hi ? b1.x : b0.x; B.y = hi ? b1.y : b0.y;
                union { uint4 u; bf16x8 v; } pun;
                pun.u.x = A.x; pun.u.y = A.y; pun.u.z = B.x; pun.u.w = B.y;
                pbf[j2][kk] = pun.v;   // P[nq=16tj+cn][nk = 8g+32kk .. +7]
            }
        }

        // ---- PV (swapped): D[d][nq]; scale by rs here ----
        {
            f32x4 o[2][2];
            #pragma unroll
            for (int ta = 0; ta < 2; ++ta)
                #pragma unroll
                for (int j2 = 0; j2 < 2; ++j2)
                    o[ta][j2] = (f32x4){0.f, 0.f, 0.f, 0.f};
            #pragma unroll
            for (int kk = 0; kk < 2; ++kk)
                #pragma unroll
                for (int ta = 0; ta < 2; ++ta)
                    #pragma unroll
                    for (int j2 = 0; j2 < 2; ++j2)
                        o[ta][j2] = MFMA16(va[ta][kk], pbf[j2][kk], o[ta][j2]);
            #pragma unroll
            for (int ta = 0; ta < 2; ++ta)
                #pragma unroll
                for (int j2 = 0; j2 < 2; ++j2) {
                    f32x4 ov = o[ta][j2];
                    const float r = rs[j2];
                    *(uint2*)&aoL[ao_off(16 * (2 * half + j2) + cn, 32 * h + 16 * ta + 4 * g)] =
                        pack4bf(ov[0] * r, ov[1] * r, ov[2] * r, ov[3] * r);
                }
        }

        // ---- T14 write-late: window 1's x (held in regs since prologue) ----
        if (rep == 0) {
            #pragma unroll
            for (int it = 0; it < 4; ++it) {
                float4 xv = xn[it];
                *(uint2*)&xb1[ao_off(an + 16 * it, 4 * ac4)] = pack4bf(xv.x, xv.y, xv.z, xv.w);
            }
        }
        __syncthreads();                 // B4: ao ready (+ xb1 ready on rep 0)

        // ---- out projection (swapped), co-block 16*(2h+half) ----
        {
            f32x4 po[4];
            #pragma unroll
            for (int tj = 0; tj < 4; ++tj)
                po[tj] = (f32x4){0.f, 0.f, 0.f, 0.f};
            const int prow = 16 * (2 * h + half) + cn;
            #pragma unroll
            for (int kc = 0; kc < 4; ++kc) {
                const bf16x8 pf = *(const bf16x8*)&wp_bf[(size_t)prow * 128 + 8 * g + 32 * kc];
                #pragma unroll
                for (int tj = 0; tj < 4; ++tj) {
                    const bf16x8 aof = *(const bf16x8*)&aoL[ao_off(16 * tj + cn, 8 * g + 32 * kc)];
                    po[tj] = MFMA16(pf, aof, po[tj]);
                }
            }
            float* og = out + (wbase + rep) * 8192;
            const int co0 = 16 * (2 * h + half) + 4 * g;
            const float4 pb4 = *(const float4*)&proj_b[co0];
            #pragma unroll
            for (int tj = 0; tj < 4; ++tj) {
                f32x4 pv = po[tj];
                float4 ov;
                ov.x = pv[0] + pb4.x; ov.y = pv[1] + pb4.y;
                ov.z = pv[2] + pb4.z; ov.w = pv[3] + pb4.w;
                *(float4*)&og[(16 * tj + cn) * 128 + co0] = ov;
            }
        }
    }
}

extern "C" void kernel_launch(void* const* d_in, const int* in_sizes, int n_in,
                              void* d_out, int out_size, void* d_ws, size_t ws_size,
                              hipStream_t stream) {
    const float* x          = (const float*)d_in[0];
    const float* qkv_w      = (const float*)d_in[1];
    const float* qkv_b      = (const float*)d_in[2];
    const float* proj_w     = (const float*)d_in[3];
    const float* proj_b     = (const float*)d_in[4];
    const float* bias_table = (const float*)d_in[5];
    float* out = (float*)d_out;

    // ws layout: [0,98304) qkv_w bf16 | [98304,131072) proj_w bf16 | [131072,163840) biasb bf16
    ushort* wq_bf = (ushort*)d_ws;
    ushort* wp_bf = (ushort*)((char*)d_ws + 98304);
    ushort* biasb = (ushort*)((char*)d_ws + 131072);

    prep_kernel<<<dim3(192), dim3(256), 0, stream>>>(qkv_w, proj_w, bias_table, wq_bf, wp_bf, biasb);
    winattn_mfma<<<dim3(2048), dim3(512), 0, stream>>>(x, qkv_b, proj_b, wq_bf, wp_bf, biasb, out);
}

// Round 9
// 114.631 us; speedup vs baseline: 1.8982x; 1.0744x over previous
//
#include <hip/hip_runtime.h>

// Window attention, bf16-MFMA (R9): permuted-layout chaining — every MFMA's
// D-layout output feeds the next MFMA's A/B fragment IN-REGISTER.
//   * d-permute pi(16i+4g+r)=8g+4i+r on wq/wk rows (prep) + bias index: QKV
//     q/k outputs, packed (i0,i1), ARE the K=32 QK^T fragments.
//   * k-token permute sigma (permuted x rows for K/V projection + permuted nk
//     in bias prep): softmax output in D-layout IS PV's B-frag; V's D[tok][d]
//     output IS PV's A-frag. Both contraction-invariant.
// 256 thr = 4 waves, wave = head, end-to-end in-register; LDS only xs/ao
// (32KB), 2 barriers, no q/k/v/P tiles, no repack shuffles (only 8 shfl_xor
// for softmax sums). launch_bounds(256,2): VGPR cap 256 -> spill impossible.

typedef __attribute__((ext_vector_type(8))) short bf16x8;
typedef __attribute__((ext_vector_type(4))) float f32x4;
typedef __attribute__((ext_vector_type(4))) __bf16 bf16x4;

#define MFMA32(a, b, c) __builtin_amdgcn_mfma_f32_16x16x32_bf16(a, b, c, 0, 0, 0)

__device__ __forceinline__ uint2 pack4bf(float a, float b, float c, float d) {
    bf16x4 v; v[0] = (__bf16)a; v[1] = (__bf16)b; v[2] = (__bf16)c; v[3] = (__bf16)d;
    union { bf16x4 v; uint2 u; } pun; pun.v = v; return pun.u;
}

__device__ __forceinline__ bf16x8 cat8(uint2 lo, uint2 hi) {
    union { uint4 u; bf16x8 v; } p;
    p.u.x = lo.x; p.u.y = lo.y; p.u.z = hi.x; p.u.w = hi.y;
    return p.v;
}

// Swizzled [64][128] bf16 tile offset (row 256B).
__device__ __forceinline__ int ao_off(int tok, int c) {
    return (tok << 7) + (((((c >> 3) & 15) ^ (tok & 7)) << 3)) + (c & 7);
}

// ---- prep: wq/wk rows d-permuted; v + proj identity; bias nk sigma-permuted ----
__global__ void prep_kernel(const float* __restrict__ qkv_w,
                            const float* __restrict__ proj_w,
                            const float* __restrict__ bias_table,
                            ushort* __restrict__ wq_bf,
                            ushort* __restrict__ wp_bf,
                            ushort* __restrict__ biasb) {
    int i = blockIdx.x * 256 + threadIdx.x;
    if (i < 49152) {
        int j = i >> 7, c = i & 127;
        int t = j >> 7, hh = (j >> 5) & 3, p = j & 31;
        int src = j;
        if (t < 2) {   // q,k: row position 16*ii+4*a+b holds weights for d = 8a+4*ii+b
            int ii = p >> 4, a = (p >> 2) & 3, b = p & 3;
            src = t * 128 + hh * 32 + 8 * a + 4 * ii + b;
        }
        union { __bf16 b; ushort s; } u; u.b = (__bf16)qkv_w[src * 128 + c];
        wq_bf[i] = u.s;
    }
    if (i < 16384) {
        union { __bf16 b; ushort s; } u; u.b = (__bf16)proj_w[i];
        wp_bf[i] = u.s;
        // biasb[((h*64+nq)*4+g)*16 + ti*4 + r]; slot (ti,g,r) holds actual
        // k-token nk = 32*(ti>>1) + 8g + 4*(ti&1) + r   (sigma permutation)
        int h = i >> 12, nq = (i >> 6) & 63, g = (i >> 4) & 3, ti = (i >> 2) & 3, r = i & 3;
        int nk = 32 * (ti >> 1) + 8 * g + 4 * (ti & 1) + r;
        int idx = ((nq >> 3) - (nk >> 3) + 7) * 15 + ((nq & 7) - (nk & 7) + 7);
        union { __bf16 b; ushort s; } ub;
        ub.b = (__bf16)(bias_table[idx * 4 + h] * 1.4426950408889634f);
        biasb[i] = ub.s;
    }
}

__global__ __launch_bounds__(256, 2)
void winattn_mfma(const float* __restrict__ x,
                  const float* __restrict__ qkv_b,
                  const float* __restrict__ proj_b,
                  const ushort* __restrict__ wq_bf,
                  const ushort* __restrict__ wp_bf,
                  const ushort* __restrict__ biasb,
                  float* __restrict__ out) {
    __shared__ ushort S[16384];    // 32KB: xs [0,8192) | ao [8192,16384)

    const int tid = threadIdx.x;
    const size_t w = blockIdx.x;
    const int h  = __builtin_amdgcn_readfirstlane(tid >> 6);  // wave = head
    const int l  = tid & 63;
    const int g  = (l >> 4) & 3;   // 0..3
    const int cn = l & 15;         // 0..15

    ushort* xs  = S;
    ushort* aoL = S + 8192;
    const f32x4 zero = (f32x4){0.f, 0.f, 0.f, 0.f};

    // ---- stage A: x -> bf16 LDS tile ----
    const float* xg = x + w * 8192;
    #pragma unroll
    for (int it = 0; it < 8; ++it) {
        int f4 = tid + 256 * it;
        int n = f4 >> 5, c4 = f4 & 31;
        float4 xv = ((const float4*)xg)[f4];
        *(uint2*)&xs[ao_off(n, 4 * c4)] = pack4bf(xv.x, xv.y, xv.z, xv.w);
    }
    __syncthreads();                              // (1) xs ready

    // ---- QKV pass A: Q (both d-halves i) ----
    uint2 qb2[2][4];                              // [i][tn] packed D-tiles
    {
        f32x4 aq[2][4];
        #pragma unroll
        for (int i = 0; i < 2; ++i)
            #pragma unroll
            for (int tn = 0; tn < 4; ++tn) aq[i][tn] = zero;
        #pragma unroll
        for (int kc = 0; kc < 4; ++kc) {
            bf16x8 xq[4];
            #pragma unroll
            for (int tn = 0; tn < 4; ++tn)
                xq[tn] = *(const bf16x8*)&xs[ao_off(16 * tn + cn, 8 * g + 32 * kc)];
            #pragma unroll
            for (int i = 0; i < 2; ++i) {
                const bf16x8 wq = *(const bf16x8*)&wq_bf[(size_t)(32 * h + 16 * i + cn) * 128 + 8 * g + 32 * kc];
                #pragma unroll
                for (int tn = 0; tn < 4; ++tn)
                    aq[i][tn] = MFMA32(wq, xq[tn], aq[i][tn]);   // D[d'][tok]
            }
        }
        #pragma unroll
        for (int i = 0; i < 2; ++i) {
            // actual d = 8g+4i+r -> bias at qkv_b[32h + 8g + 4i + r]
            const float4 bq = *(const float4*)&qkv_b[32 * h + 8 * g + 4 * i];
            #pragma unroll
            for (int tn = 0; tn < 4; ++tn) {
                f32x4 q4 = aq[i][tn];
                qb2[i][tn] = pack4bf(q4[0] + bq.x, q4[1] + bq.y, q4[2] + bq.z, q4[3] + bq.w);
            }
        }
    }

    // ---- QKV pass B: K, V (K via sigma-permuted x rows; V same rows) ----
    uint2 kb2[2][4], vb2[4][2];
    {
        f32x4 ak[2][4], av[4][2];
        #pragma unroll
        for (int i = 0; i < 2; ++i)
            #pragma unroll
            for (int tn = 0; tn < 4; ++tn) { ak[i][tn] = zero; av[tn][i] = zero; }
        #pragma unroll
        for (int kc = 0; kc < 4; ++kc) {
            bf16x8 xkv[4];
            #pragma unroll
            for (int tn = 0; tn < 4; ++tn) {
                const int row = 32 * (tn >> 1) + 8 * (cn >> 2) + 4 * (tn & 1) + (cn & 3);
                xkv[tn] = *(const bf16x8*)&xs[ao_off(row, 8 * g + 32 * kc)];
            }
            #pragma unroll
            for (int i = 0; i < 2; ++i) {
                const bf16x8 wk = *(const bf16x8*)&wq_bf[(size_t)(128 + 32 * h + 16 * i + cn) * 128 + 8 * g + 32 * kc];
                const bf16x8 wv = *(const bf16x8*)&wq_bf[(size_t)(256 + 32 * h + 16 * i + cn) * 128 + 8 * g + 32 * kc];
                #pragma unroll
                for (int tn = 0; tn < 4; ++tn) {
                    ak[i][tn] = MFMA32(wk, xkv[tn], ak[i][tn]);   // D[d'][tok-slot]
                    av[tn][i] = MFMA32(xkv[tn], wv, av[tn][i]);   // D[tok-slot][d]
                }
            }
        }
        #pragma unroll
        for (int i = 0; i < 2; ++i) {
            const float4 bk = *(const float4*)&qkv_b[128 + 32 * h + 8 * g + 4 * i];
            const float  bv = qkv_b[256 + 32 * h + 16 * i + cn];
            #pragma unroll
            for (int tn = 0; tn < 4; ++tn) {
                f32x4 k4 = ak[i][tn], v4 = av[tn][i];
                kb2[i][tn] = pack4bf(k4[0] + bk.x, k4[1] + bk.y, k4[2] + bk.z, k4[3] + bk.w);
                vb2[tn][i] = pack4bf(v4[0] + bv, v4[1] + bv, v4[2] + bv, v4[3] + bv);
            }
        }
    }

    // ---- assemble K=32 fragments (pure register re-pairing) ----
    bf16x8 kb[4], qb[4], vA[2][2];
    #pragma unroll
    for (int t = 0; t < 4; ++t) {
        kb[t] = cat8(kb2[0][t], kb2[1][t]);   // A-frag: k[d=8g+4i+r][tok-slot 16t+cn]
        qb[t] = cat8(qb2[0][t], qb2[1][t]);   // B-frag: q[d=8g+4i+r][nq=16t+cn]
    }
    #pragma unroll
    for (int kk = 0; kk < 2; ++kk)
        #pragma unroll
        for (int ta = 0; ta < 2; ++ta)
            vA[kk][ta] = cat8(vb2[2 * kk][ta], vb2[2 * kk + 1][ta]);  // A-frag: v[tok 32kk+8g+4u+r][d=16ta+cn]

    // ---- attention: QK^T -> softmax -> PV, per tj-pair (bounds live regs) ----
    const float SCALE2 = 0.17677669529663687f * 1.4426950408889634f;  // scale*log2(e)
    #pragma unroll
    for (int tjg = 0; tjg < 2; ++tjg) {
        f32x4 s[4][2];
        #pragma unroll
        for (int ti = 0; ti < 4; ++ti)
            #pragma unroll
            for (int j2 = 0; j2 < 2; ++j2)
                s[ti][j2] = MFMA32(kb[ti], qb[2 * tjg + j2], zero);  // S D[slot][nq], K=32 over d

        uint4 bb[2][2];
        #pragma unroll
        for (int j2 = 0; j2 < 2; ++j2) {
            const int nq = 16 * (2 * tjg + j2) + cn;
            const ushort* bp = biasb + (((h * 64 + nq) * 4 + g) << 4);
            bb[j2][0] = *(const uint4*)bp;
            bb[j2][1] = *(const uint4*)(bp + 8);
        }

        uint2 pkt[2][4];
        float rs[2];
        #pragma unroll
        for (int j2 = 0; j2 < 2; ++j2) {
            float sum = 0.f;
            #pragma unroll
            for (int ti = 0; ti < 4; ++ti) {
                const uint4 q4 = bb[j2][ti >> 1];
                const unsigned w0 = (ti & 1) ? q4.z : q4.x;
                const unsigned w1 = (ti & 1) ? q4.w : q4.y;
                const float b0 = __uint_as_float(w0 << 16);
                const float b1 = __uint_as_float(w0 & 0xffff0000u);
                const float b2 = __uint_as_float(w1 << 16);
                const float b3 = __uint_as_float(w1 & 0xffff0000u);
                f32x4 sv = s[ti][j2];
                sv[0] = exp2f(fmaf(sv[0], SCALE2, b0));
                sv[1] = exp2f(fmaf(sv[1], SCALE2, b1));
                sv[2] = exp2f(fmaf(sv[2], SCALE2, b2));
                sv[3] = exp2f(fmaf(sv[3], SCALE2, b3));
                pkt[j2][ti] = pack4bf(sv[0], sv[1], sv[2], sv[3]);   // = PV B-frag piece
                sum += (sv[0] + sv[1]) + (sv[2] + sv[3]);
            }
            sum += __shfl_xor(sum, 16, 64);
            sum += __shfl_xor(sum, 32, 64);
            rs[j2] = 1.0f / sum;                 // folded into PV epilogue (lane-local)
        }

        #pragma unroll
        for (int j2 = 0; j2 < 2; ++j2) {
            const bf16x8 p0 = cat8(pkt[j2][0], pkt[j2][1]);   // B-frag, tokens 0..31
            const bf16x8 p1 = cat8(pkt[j2][2], pkt[j2][3]);   // B-frag, tokens 32..63
            const float r = rs[j2];
            #pragma unroll
            for (int ta = 0; ta < 2; ++ta) {
                f32x4 o = MFMA32(vA[0][ta], p0, zero);
                o = MFMA32(vA[1][ta], p1, o);                 // D[d][nq]
                *(uint2*)&aoL[ao_off(16 * (2 * tjg + j2) + cn, 32 * h + 16 * ta + 4 * g)] =
                    pack4bf(o[0] * r, o[1] * r, o[2] * r, o[3] * r);
            }
        }
    }
    __syncthreads();                              // (2) ao ready

    // ---- out projection (swapped): D[co][tok], wave h -> co tiles {2h, 2h+1} ----
    float* og = out + w * 8192;
    #pragma unroll
    for (int i = 0; i < 2; ++i) {
        const int prow = 16 * (2 * h + i) + cn;
        f32x4 po[4];
        #pragma unroll
        for (int tj = 0; tj < 4; ++tj) po[tj] = zero;
        #pragma unroll
        for (int kc = 0; kc < 4; ++kc) {
            const bf16x8 pf = *(const bf16x8*)&wp_bf[(size_t)prow * 128 + 8 * g + 32 * kc];
            #pragma unroll
            for (int tj = 0; tj < 4; ++tj) {
                const bf16x8 aof = *(const bf16x8*)&aoL[ao_off(16 * tj + cn, 8 * g + 32 * kc)];
                po[tj] = MFMA32(pf, aof, po[tj]);
            }
        }
        const int co0 = 16 * (2 * h + i) + 4 * g;
        const float4 pb4 = *(const float4*)&proj_b[co0];
        #pragma unroll
        for (int tj = 0; tj < 4; ++tj) {
            f32x4 pv = po[tj];
            float4 ov;
            ov.x = pv[0] + pb4.x; ov.y = pv[1] + pb4.y;
            ov.z = pv[2] + pb4.z; ov.w = pv[3] + pb4.w;
            *(float4*)&og[(16 * tj + cn) * 128 + co0] = ov;
        }
    }
}

extern "C" void kernel_launch(void* const* d_in, const int* in_sizes, int n_in,
                              void* d_out, int out_size, void* d_ws, size_t ws_size,
                              hipStream_t stream) {
    const float* x          = (const float*)d_in[0];
    const float* qkv_w      = (const float*)d_in[1];
    const float* qkv_b      = (const float*)d_in[2];
    const float* proj_w     = (const float*)d_in[3];
    const float* proj_b     = (const float*)d_in[4];
    const float* bias_table = (const float*)d_in[5];
    float* out = (float*)d_out;

    // ws layout: [0,98304) qkv_w bf16 (q/k rows d-permuted) | [98304,131072) proj_w bf16
    //            [131072,163840) biasb bf16 (nk sigma-permuted)
    ushort* wq_bf = (ushort*)d_ws;
    ushort* wp_bf = (ushort*)((char*)d_ws + 98304);
    ushort* biasb = (ushort*)((char*)d_ws + 131072);

    prep_kernel<<<dim3(192), dim3(256), 0, stream>>>(qkv_w, proj_w, bias_table, wq_bf, wp_bf, biasb);
    winattn_mfma<<<dim3(4096), dim3(256), 0, stream>>>(x, qkv_b, proj_b, wq_bf, wp_bf, biasb, out);
}